// Round 3
// baseline (137.738 us; speedup 1.0000x reference)
//
#include <hip/hip_runtime.h>
#include <hip/hip_bf16.h>

// Geometry
#define NW 64          // N*W = 4*16
#define P 128          // rows per (n,w)
#define D 96           // channels
#define PD (P*D)
#define GCH 101
#define SIM 100
#define LCH 80
#define RSQRT96 0.10206207261596577f   // 1/sqrt(96)

// ws layout (float offsets)
#define WS_SCALE 0                     // 128 floats
#define WS_Q     128                   // 64*128*96   [r][c]
#define WS_KT    (128 + 786432)        // 64*96*128   [c][r] transposed
#define WS_VO    (128 + 2*786432)      // 64*128*96   [r][c]

typedef unsigned long long ull;

// Monotone (value desc would be key desc; here ascending uint order == float order)
// key = (ordered_u32(value) << 32) | (127 - idx): strict total order, ties -> lower idx wins.
__device__ __forceinline__ ull make_key(float a, int idx) {
  unsigned u = __float_as_uint(a);
  unsigned msk = (u & 0x80000000u) ? 0xFFFFFFFFu : 0x80000000u;
  return (((ull)(u ^ msk)) << 32) | (unsigned)(127 - idx);
}

// Proj: lane = output channel, W row in VGPRs, V row via scalar loads (uniform).
// grid: nw*6 + pj*2 + half; block 128 thr (96 compute channels).
// pj=0 -> Q = scale0*(vq@Wq^T)+b_q  [r][c];  pj=1 -> K^T [c][r] via LDS bounce;
// pj=2 -> VO = vq@Wo^T [r][c].  Block 0 also writes the 101 sigmoid scales.
__global__ __launch_bounds__(128) void proj_kernel(const float* __restrict__ v,
    const float* __restrict__ wq, const float* __restrict__ bq,
    const float* __restrict__ wk, const float* __restrict__ wo,
    const float* __restrict__ mb, const float* __restrict__ w_up,
    const float* __restrict__ b_up, float* __restrict__ ws) {
  int bid = blockIdx.x;
  int nw = bid / 6;
  int rem = bid - nw * 6;
  int pj = rem >> 1, half = rem & 1;
  int t = threadIdx.x;
  const float* W = (pj == 0) ? wq : (pj == 1) ? wk : wo;
  float wreg[96];
  {
    const float4* wp = (const float4*)(W + (t < 96 ? t : 0) * 96);
#pragma unroll
    for (int i = 0; i < 24; ++i) {
      float4 x = wp[i];
      wreg[4*i+0] = x.x; wreg[4*i+1] = x.y; wreg[4*i+2] = x.z; wreg[4*i+3] = x.w;
    }
  }
  float scale0 = 0.f, bias = 0.f;
  if (pj == 0) {
    float a = b_up[0];
    for (int j = 0; j < LCH; ++j) a += w_up[j] * mb[j];   // uniform -> scalar
    scale0 = 1.f / (1.f + __expf(-a));
    bias = (t < 96) ? bq[t] : 0.f;
  }
  __shared__ float sK[96 * 65];   // transpose bounce (pj==1 only), conflict-free
  const float* Vb = v + (size_t)(nw * P + half * 64) * D;
  float* outp = ws + ((pj == 0) ? WS_Q : (pj == 1) ? WS_KT : WS_VO) + nw * PD;
  for (int r = 0; r < 64; ++r) {
    const float* Vr = Vb + r * D;   // uniform address -> s_load stream
    float a0 = 0.f, a1 = 0.f, a2 = 0.f, a3 = 0.f;   // break FMA dep chain
#pragma unroll
    for (int i = 0; i < 24; ++i) {
      a0 += Vr[4*i+0] * wreg[4*i+0];
      a1 += Vr[4*i+1] * wreg[4*i+1];
      a2 += Vr[4*i+2] * wreg[4*i+2];
      a3 += Vr[4*i+3] * wreg[4*i+3];
    }
    float acc = (a0 + a1) + (a2 + a3);
    if (t < 96) {
      if (pj == 0)      outp[(half*64 + r) * D + t] = scale0 * acc + bias;
      else if (pj == 2) outp[(half*64 + r) * D + t] = acc;
      else              sK[t * 65 + r] = acc;   // stride 65: conflict-free
    }
  }
  if (pj == 1) {
    __syncthreads();
    for (int idx = t; idx < 96 * 64; idx += 128) {
      int c = idx >> 6, r = idx & 63;
      outp[c * P + half * 64 + r] = sK[c * 65 + r];   // coalesced 64-float runs
    }
  }
  if (bid == 0 && t < GCH) {
    float a = b_up[t];
    for (int j = 0; j < LCH; ++j) a += w_up[t * LCH + j] * mb[j];
    ws[WS_SCALE + t] = 1.f / (1.f + __expf(-a));
  }
}

// Attn: 1 wave = 4 rows, lane owns columns {lane, 64+lane}. Zero LDS.
// Rank via u64-key compare against SALU-built uniform keys; T broadcast via readlane.
// grid = 64 nw * 8 row-tiles; block 256 thr = 4 independent waves (16 rows/block).
__global__ __launch_bounds__(256) void attn_kernel(const float* __restrict__ attn,
    const float* __restrict__ bo, const float* __restrict__ ws,
    float* __restrict__ out) {
  int tid = threadIdx.x;
  int wv = tid >> 6, lane = tid & 63;
  int nw = blockIdx.x >> 3;
  int rt = blockIdx.x & 7;
  int p0 = rt * 16 + wv * 4;
  const float* Kt  = ws + WS_KT + nw * PD;
  const float* VO  = ws + WS_VO + nw * PD;
  const float* Qb  = ws + WS_Q  + nw * PD + p0 * D;
  const float* Ab  = attn + (size_t)(nw * P + p0) * P;
  const float* scl = ws + WS_SCALE;

  // per-lane keys for my 2 columns of each of 4 rows
  ull k0[4], k1[4];
#pragma unroll
  for (int r = 0; r < 4; ++r) {
    k0[r] = make_key(Ab[r * P + lane], lane);
    k1[r] = make_key(Ab[r * P + 64 + lane], 64 + lane);
  }

  // S[r][col] = q_r . k_col ; q from scalar loads, Kt coalesced per-lane
  float s0[4] = {0,0,0,0}, s1[4] = {0,0,0,0};
#pragma unroll 8
  for (int c = 0; c < D; ++c) {
    float kv0 = Kt[c * P + lane];
    float kv1 = Kt[c * P + 64 + lane];
#pragma unroll
    for (int r = 0; r < 4; ++r) {
      float q = Qb[r * D + c];     // uniform -> s_load
      s0[r] += q * kv0;
      s1[r] += q * kv1;
    }
  }

  // exact stable top-100 rank: cnt = #{j : key_j > my_key}
  int c0[4] = {0,0,0,0}, c1[4] = {0,0,0,0};
#pragma unroll 4
  for (int j = 0; j < P; ++j) {
#pragma unroll
    for (int r = 0; r < 4; ++r) {
      ull kj = make_key(Ab[r * P + j], j);   // uniform: SALU build, v_cmp vs sgpr-pair
      c0[r] += (kj > k0[r]) ? 1 : 0;
      c1[r] += (kj > k1[r]) ? 1 : 0;
    }
  }

  // keep mask, in-wave position, scale gather, softmax, T weights
  float t0[4], t1[4];
  ull lm = (1ull << lane) - 1ull;
#pragma unroll
  for (int r = 0; r < 4; ++r) {
    bool kp0 = c0[r] < SIM, kp1 = c1[r] < SIM;
    ull b0 = __ballot(kp0), b1 = __ballot(kp1);
    int pos0 = __popcll(b0 & lm);
    int pos1 = __popcll(b0) + __popcll(b1 & lm);
    float sv0 = kp0 ? scl[1 + pos0] : 0.f;
    float sv1 = kp1 ? scl[1 + pos1] : 0.f;
    float x0 = kp0 ? sv0 * s0[r] * RSQRT96 : -1e30f;
    float x1 = kp1 ? sv1 * s1[r] * RSQRT96 : -1e30f;
    float m = fmaxf(x0, x1);
#pragma unroll
    for (int off = 1; off < 64; off <<= 1) m = fmaxf(m, __shfl_xor(m, off));
    float e0 = kp0 ? __expf(x0 - m) : 0.f;
    float e1 = kp1 ? __expf(x1 - m) : 0.f;
    float s = e0 + e1;
#pragma unroll
    for (int off = 1; off < 64; off <<= 1) s += __shfl_xor(s, off);
    float inv = 1.f / s;
    t0[r] = e0 * inv * sv0;
    t1[r] = e1 * inv * sv1;
  }

  // out[r][c] = sum_j T[r][j] * VO[j][c] + b_o[c]; T via readlane (VALU, no LDS)
  float o0[4] = {0,0,0,0}, o1[4] = {0,0,0,0};
  int lane2 = (lane < 32) ? (64 + lane) : 95;   // clamp: inactive lanes read junk, unused
#pragma unroll 4
  for (int j = 0; j < 64; ++j) {
    float vo0 = VO[j * D + lane];
    float vo1 = VO[j * D + lane2];
#pragma unroll
    for (int r = 0; r < 4; ++r) {
      float tv = __int_as_float(__builtin_amdgcn_readlane(__float_as_int(t0[r]), j));
      o0[r] += tv * vo0;
      o1[r] += tv * vo1;
    }
  }
#pragma unroll 4
  for (int j = 0; j < 64; ++j) {
    float vo0 = VO[(64 + j) * D + lane];
    float vo1 = VO[(64 + j) * D + lane2];
#pragma unroll
    for (int r = 0; r < 4; ++r) {
      float tv = __int_as_float(__builtin_amdgcn_readlane(__float_as_int(t1[r]), j));
      o0[r] += tv * vo0;
      o1[r] += tv * vo1;
    }
  }
  float bb0 = bo[lane];
  float bb1 = bo[lane2];
  float* op = out + (size_t)(nw * P + p0) * D;
#pragma unroll
  for (int r = 0; r < 4; ++r) {
    op[r * D + lane] = o0[r] + bb0;
    if (lane < 32) op[r * D + 64 + lane] = o1[r] + bb1;
  }
}

extern "C" void kernel_launch(void* const* d_in, const int* in_sizes, int n_in,
                              void* d_out, int out_size, void* d_ws, size_t ws_size,
                              hipStream_t stream) {
  const float* attn = (const float*)d_in[0];
  const float* v    = (const float*)d_in[1];
  const float* mb   = (const float*)d_in[2];
  // d_in[3]=w_sub, d_in[4]=b_sub: dead (softmax over singleton axis == 1)
  const float* w_up = (const float*)d_in[5];
  const float* b_up = (const float*)d_in[6];
  const float* w_q  = (const float*)d_in[7];
  const float* b_q  = (const float*)d_in[8];
  const float* w_k  = (const float*)d_in[9];
  // d_in[10]=b_k: constant shift per row -> drops out of softmax, unused
  const float* w_o  = (const float*)d_in[11];
  const float* b_o  = (const float*)d_in[12];
  float* out = (float*)d_out;
  float* ws = (float*)d_ws;

  hipLaunchKernelGGL(proj_kernel, dim3(NW * 6), dim3(128), 0, stream,
                     v, w_q, b_q, w_k, w_o, mb, w_up, b_up, ws);
  hipLaunchKernelGGL(attn_kernel, dim3(NW * 8), dim3(256), 0, stream,
                     attn, b_o, ws, out);
}

// Round 4
// 107.112 us; speedup vs baseline: 1.2859x; 1.2859x over previous
//
#include <hip/hip_runtime.h>
#include <hip/hip_bf16.h>

// Geometry
#define NW 64          // N*W = 4*16
#define P 128          // rows per (n,w)
#define D 96           // channels
#define PD (P*D)
#define GCH 101
#define SIM 100
#define LCH 80
#define RSQRT96 0.10206207261596577f   // 1/sqrt(96)

// ws layout (float offsets)
#define WS_SCALE 0                     // 128 floats
#define WS_Q     128                   // 64*128*96   [r][c]
#define WS_KT    (128 + 786432)        // 64*96*128   [c][r] transposed
#define WS_VO    (128 + 2*786432)      // 64*128*96   [r][c]

typedef unsigned long long ull;

// key = (ordered_u32(value) << 32) | (127 - idx): strict total order,
// ties -> lower idx wins. Matches top_k + sort-index semantics exactly.
__device__ __forceinline__ ull make_key(float a, int idx) {
  unsigned u = __float_as_uint(a);
  unsigned msk = (u & 0x80000000u) ? 0xFFFFFFFFu : 0x80000000u;
  return (((ull)(u ^ msk)) << 32) | (unsigned)(127 - idx);
}

// Proj: lane = row. V row in VGPRs (static-indexed, launch_bounds caps occupancy
// so no spill), W streamed via wave-uniform scalar loads in 32-float chunks.
// grid: (nw, pj, chalf): 64*3*2 = 384 blocks, 128 thr (2 waves = 2 row-halves).
// pj=0 -> Q = scale0*(vq@Wq^T)+b_q; pj=1 -> K^T [c][r] (direct coalesced store);
// pj=2 -> VO = vq@Wo^T. Block 0 writes the 101 sigmoid scales.
__global__ __launch_bounds__(128, 2) void proj_kernel(const float* __restrict__ v,
    const float* __restrict__ wq, const float* __restrict__ bq,
    const float* __restrict__ wk, const float* __restrict__ wo,
    const float* __restrict__ mb, const float* __restrict__ w_up,
    const float* __restrict__ b_up, float* __restrict__ ws) {
  int bid = blockIdx.x;
  int nw = bid / 6;
  int rem = bid - nw * 6;
  int pj = rem >> 1, ch = rem & 1;
  int c0 = ch * 48;
  const float* W = (pj == 0) ? wq : (pj == 1) ? wk : wo;
  __shared__ float sV[128 * 97];   // stage buffer; later reused as output bounce
  int t = threadIdx.x;
  int wv = t >> 6, lane = t & 63;

  // stage V[128][96] -> sV[r*97+d] (coalesced float4 global reads; each float4
  // stays within one row since 96%4==0)
  const float* Vg = v + (size_t)nw * PD;
#pragma unroll
  for (int i = 0; i < 24; ++i) {
    int idx = (t + 128 * i) * 4;
    float4 x = *(const float4*)(Vg + idx);
    int r = idx / 96, d = idx - r * 96;
    sV[r * 97 + d + 0] = x.x; sV[r * 97 + d + 1] = x.y;
    sV[r * 97 + d + 2] = x.z; sV[r * 97 + d + 3] = x.w;
  }
  __syncthreads();

  // my row's V into registers: stride-97 b32 reads, 2 lanes/bank = conflict-free
  int r = (wv << 6) | lane;
  float vreg[96];
#pragma unroll
  for (int d = 0; d < 96; ++d) vreg[d] = sV[r * 97 + d];

  float scale0 = 0.f;
  if (pj == 0) {   // uniform scalar compute
    float a = b_up[0];
    for (int j = 0; j < LCH; ++j) a += w_up[j] * mb[j];
    scale0 = 1.f / (1.f + __expf(-a));
  }

  // output bounce region: wave-private (inside this wave's already-consumed
  // half of sV; per-wave LDS ops are in-order, so no barrier needed)
  float* sO = sV + wv * (64 * 97);
  const float* Wb = W + (size_t)c0 * 96;
  float* ktp = ws + WS_KT + nw * PD;

  for (int ci = 0; ci < 48; ++ci) {
    const float* Wr = Wb + ci * 96;    // uniform -> s_load stream
    float a0 = 0.f, a1 = 0.f, a2 = 0.f, a3 = 0.f;
    for (int dd = 0; dd < 96; dd += 32) {   // chunked: bounds SGPR pressure
      float w[32];
#pragma unroll
      for (int i = 0; i < 32; ++i) w[i] = Wr[dd + i];
#pragma unroll
      for (int i = 0; i < 32; i += 4) {
        a0 += vreg[dd + i + 0] * w[i + 0];
        a1 += vreg[dd + i + 1] * w[i + 1];
        a2 += vreg[dd + i + 2] * w[i + 2];
        a3 += vreg[dd + i + 3] * w[i + 3];
      }
    }
    float acc = (a0 + a1) + (a2 + a3);
    if (pj == 0) acc = scale0 * acc + bq[c0 + ci];
    if (pj == 1) {
      // lanes are consecutive rows -> 256B coalesced store, no bounce needed
      ktp[(c0 + ci) * P + r] = acc;
    } else {
      sO[lane * 49 + ci] = acc;   // stride 49 (odd): conflict-free
    }
  }

  if (pj != 1) {   // coalesced flush of [64 rows][48 cols] bounce
    float* outp = ws + ((pj == 0) ? WS_Q : WS_VO) + nw * PD + (wv << 6) * D;
    if (lane < 48) {
      for (int rr = 0; rr < 64; ++rr)
        outp[rr * D + c0 + lane] = sO[rr * 49 + lane];
    }
  }

  if (bid == 0 && t < GCH) {
    float a = b_up[t];
    for (int j = 0; j < LCH; ++j) a += w_up[t * LCH + j] * mb[j];
    ws[WS_SCALE + t] = 1.f / (1.f + __expf(-a));
  }
}

// Attn: 1-wave blocks (64 thr) so all per-row data is block-uniform -> SALU/s_load.
// Lane owns columns {lane, 64+lane} of 4 rows. Zero LDS. Rank via u64 keys
// (uniform side SALU-built), softmax in-wave, PV via readlane broadcast.
__global__ __launch_bounds__(64, 2) void attn_kernel(const float* __restrict__ attn,
    const float* __restrict__ bo, const float* __restrict__ ws,
    float* __restrict__ out) {
  int lane = threadIdx.x;
  int nw = blockIdx.x >> 5;
  int p0 = (blockIdx.x & 31) << 2;
  const float* Kt  = ws + WS_KT + nw * PD;
  const float* VO  = ws + WS_VO + nw * PD;
  const float* Qb  = ws + WS_Q  + nw * PD + p0 * D;
  const float* Ab  = attn + (size_t)(nw * P + p0) * P;
  const float* scl = ws + WS_SCALE;

  // per-lane keys for my 2 columns of each of 4 rows
  ull k0[4], k1[4];
#pragma unroll
  for (int r = 0; r < 4; ++r) {
    k0[r] = make_key(Ab[r * P + lane], lane);
    k1[r] = make_key(Ab[r * P + 64 + lane], 64 + lane);
  }

  // exact stable top-100 rank; uniform A loads chunked (8/row) to stay in SGPRs
  int c0_[4] = {0,0,0,0}, c1_[4] = {0,0,0,0};
  for (int jb = 0; jb < P; jb += 8) {
    float aj[4][8];
#pragma unroll
    for (int rr = 0; rr < 4; ++rr)
#pragma unroll
      for (int i = 0; i < 8; ++i) aj[rr][i] = Ab[rr * P + jb + i];
#pragma unroll
    for (int i = 0; i < 8; ++i) {
      int j = jb + i;
#pragma unroll
      for (int rr = 0; rr < 4; ++rr) {
        ull kj = make_key(aj[rr][i], j);   // uniform: SALU build
        c0_[rr] += (kj > k0[rr]) ? 1 : 0;  // v_cmp_gt_u64 + addc
        c1_[rr] += (kj > k1[rr]) ? 1 : 0;
      }
    }
  }

  // S[r][col] = q_r . k_col ; q uniform (chunked), Kt coalesced per-lane
  float s0[4] = {0,0,0,0}, s1[4] = {0,0,0,0};
  for (int cb = 0; cb < D; cb += 8) {
    float q[4][8];
#pragma unroll
    for (int rr = 0; rr < 4; ++rr)
#pragma unroll
      for (int i = 0; i < 8; ++i) q[rr][i] = Qb[rr * D + cb + i];
#pragma unroll
    for (int i = 0; i < 8; ++i) {
      int c = cb + i;
      float kv0 = Kt[c * P + lane];
      float kv1 = Kt[c * P + 64 + lane];
#pragma unroll
      for (int rr = 0; rr < 4; ++rr) {
        s0[rr] += q[rr][i] * kv0;
        s1[rr] += q[rr][i] * kv1;
      }
    }
  }

  // keep mask, position among kept, scale gather, softmax, T weights
  float t0[4], t1[4];
  ull lm = (1ull << lane) - 1ull;
#pragma unroll
  for (int rr = 0; rr < 4; ++rr) {
    bool kp0 = c0_[rr] < SIM, kp1 = c1_[rr] < SIM;
    ull b0 = __ballot(kp0), b1 = __ballot(kp1);
    int pos0 = __popcll(b0 & lm);
    int pos1 = __popcll(b0) + __popcll(b1 & lm);
    float sv0 = kp0 ? scl[1 + pos0] : 0.f;
    float sv1 = kp1 ? scl[1 + pos1] : 0.f;
    float x0 = kp0 ? sv0 * s0[rr] * RSQRT96 : -1e30f;
    float x1 = kp1 ? sv1 * s1[rr] * RSQRT96 : -1e30f;
    float m = fmaxf(x0, x1);
#pragma unroll
    for (int off = 1; off < 64; off <<= 1) m = fmaxf(m, __shfl_xor(m, off));
    float e0 = kp0 ? __expf(x0 - m) : 0.f;
    float e1 = kp1 ? __expf(x1 - m) : 0.f;
    float s = e0 + e1;
#pragma unroll
    for (int off = 1; off < 64; off <<= 1) s += __shfl_xor(s, off);
    float inv = 1.f / s;
    t0[rr] = e0 * inv * sv0;
    t1[rr] = e1 * inv * sv1;
  }

  // out[r][c] = sum_j T[r][j] * VO[j][c] + b_o[c]; T broadcast via readlane
  float o0[4] = {0,0,0,0}, o1[4] = {0,0,0,0};
  int lane2 = (lane < 32) ? (64 + lane) : 95;  // clamp; junk unused
#pragma unroll 4
  for (int j = 0; j < 64; ++j) {
    float vo0 = VO[j * D + lane];
    float vo1 = VO[j * D + lane2];
#pragma unroll
    for (int rr = 0; rr < 4; ++rr) {
      float tv = __int_as_float(__builtin_amdgcn_readlane(__float_as_int(t0[rr]), j));
      o0[rr] += tv * vo0;
      o1[rr] += tv * vo1;
    }
  }
#pragma unroll 4
  for (int j = 0; j < 64; ++j) {
    float vo0 = VO[(64 + j) * D + lane];
    float vo1 = VO[(64 + j) * D + lane2];
#pragma unroll
    for (int rr = 0; rr < 4; ++rr) {
      float tv = __int_as_float(__builtin_amdgcn_readlane(__float_as_int(t1[rr]), j));
      o0[rr] += tv * vo0;
      o1[rr] += tv * vo1;
    }
  }
  float bb0 = bo[lane];
  float bb1 = bo[lane2];
  float* op = out + (size_t)(nw * P + p0) * D;
#pragma unroll
  for (int rr = 0; rr < 4; ++rr) {
    op[rr * D + lane] = o0[rr] + bb0;
    if (lane < 32) op[rr * D + 64 + lane] = o1[rr] + bb1;
  }
}

extern "C" void kernel_launch(void* const* d_in, const int* in_sizes, int n_in,
                              void* d_out, int out_size, void* d_ws, size_t ws_size,
                              hipStream_t stream) {
  const float* attn = (const float*)d_in[0];
  const float* v    = (const float*)d_in[1];
  const float* mb   = (const float*)d_in[2];
  // d_in[3]=w_sub, d_in[4]=b_sub: dead (softmax over singleton axis == 1)
  const float* w_up = (const float*)d_in[5];
  const float* b_up = (const float*)d_in[6];
  const float* w_q  = (const float*)d_in[7];
  const float* b_q  = (const float*)d_in[8];
  const float* w_k  = (const float*)d_in[9];
  // d_in[10]=b_k: constant shift per row -> drops out of softmax, unused
  const float* w_o  = (const float*)d_in[11];
  const float* b_o  = (const float*)d_in[12];
  float* out = (float*)d_out;
  float* ws = (float*)d_ws;

  hipLaunchKernelGGL(proj_kernel, dim3(NW * 6), dim3(128), 0, stream,
                     v, w_q, b_q, w_k, w_o, mb, w_up, b_up, ws);
  hipLaunchKernelGGL(attn_kernel, dim3(NW * 32), dim3(64), 0, stream,
                     attn, b_o, ws, out);
}

// Round 5
// 67.766 us; speedup vs baseline: 2.0325x; 1.5806x over previous
//
#include <hip/hip_runtime.h>
#include <hip/hip_bf16.h>

// Geometry
#define NW 64          // N*W = 4*16
#define P 128          // rows per (n,w)
#define D 96           // channels
#define PD (P*D)
#define GCH 101
#define SIM 100
#define LCH 80
#define RSQRT96 0.10206207261596577f   // 1/sqrt(96)

// ws layout (float offsets)
#define WS_SCALE 0                     // 128 floats
#define WS_Q     128                   // 64*128*96   [r][c]
#define WS_KT    (128 + 786432)        // 64*96*128   [c][r] transposed
#define WS_VO    (128 + 2*786432)      // 64*128*96   [r][c]

typedef unsigned long long ull;

// key = (ordered_u32(value) << 32) | (127 - idx): strict total order,
// ties -> lower idx wins. Matches top_k + sort-index semantics exactly.
__device__ __forceinline__ ull make_key(float a, int idx) {
  unsigned u = __float_as_uint(a);
  unsigned msk = (u & 0x80000000u) ? 0xFFFFFFFFu : 0x80000000u;
  return (((ull)(u ^ msk)) << 32) | (unsigned)(127 - idx);
}

// Proj: LDS-tiled GEMM, register tile 4 rows x 12 cols per thread.
// grid: nw*6 + pj*2 + rh (384 blocks), 128 thr = 2 waves.
// Block computes 64 rows (rh half) x 96 cols of one projection.
//   pj=0 -> Q = scale0*(vq@Wq^T)+b_q [r][c]
//   pj=1 -> K^T [c][r]
//   pj=2 -> VO = vq@Wo^T [r][c]
// LDS: sWt[96][100] (38400B, b128-aligned conflict-free) + sV[64][97] (24832B).
__global__ __launch_bounds__(128, 4) void proj_kernel(const float* __restrict__ v,
    const float* __restrict__ wq, const float* __restrict__ bq,
    const float* __restrict__ wk, const float* __restrict__ wo,
    const float* __restrict__ mb, const float* __restrict__ w_up,
    const float* __restrict__ b_up, float* __restrict__ ws) {
  int bid = blockIdx.x;
  int nw = bid / 6;
  int rem = bid - nw * 6;
  int pj = rem >> 1, rh = rem & 1;
  const float* W = (pj == 0) ? wq : (pj == 1) ? wk : wo;
  __shared__ float sWt[96 * 100];   // [d][c] stride 100: 16B-aligned rows
  __shared__ float sV[64 * 97];     // [r][d] stride 97: conflict-free b32
  int t = threadIdx.x;
  int ty = t >> 3;   // 0..15 -> row group of 4
  int tx = t & 7;    // 0..7  -> col group of 12

  // stage W transposed: coalesced global read, scattered LDS write (once)
  for (int k = 0; k < 72; ++k) {
    int idx = t + 128 * k;
    int c = idx / 96, d = idx - c * 96;
    sWt[d * 100 + c] = W[idx];
  }
  // stage V half: coalesced float4 reads (rows are 96 floats, 96%4==0)
  const float* Vg = v + (size_t)nw * PD + rh * (64 * D);
#pragma unroll
  for (int i = 0; i < 12; ++i) {
    int idx = (t + 128 * i) * 4;
    float4 x = *(const float4*)(Vg + idx);
    int r = idx / 96, d = idx - r * 96;
    float* p = &sV[r * 97 + d];
    p[0] = x.x; p[1] = x.y; p[2] = x.z; p[3] = x.w;
  }
  float scale0 = 0.f;
  if (pj == 0) {   // uniform
    float a = b_up[0];
    for (int j = 0; j < LCH; ++j) a += w_up[j] * mb[j];
    scale0 = 1.f / (1.f + __expf(-a));
  }
  __syncthreads();

  float acc[4][12];
#pragma unroll
  for (int a = 0; a < 4; ++a)
#pragma unroll
    for (int j = 0; j < 12; ++j) acc[a][j] = 0.f;

  for (int d = 0; d < 96; ++d) {
    float va0 = sV[(ty * 4 + 0) * 97 + d];
    float va1 = sV[(ty * 4 + 1) * 97 + d];
    float va2 = sV[(ty * 4 + 2) * 97 + d];
    float va3 = sV[(ty * 4 + 3) * 97 + d];
    const float4* wp = (const float4*)&sWt[d * 100 + tx * 12];
    float4 w0 = wp[0], w1 = wp[1], w2 = wp[2];
    float wb[12] = {w0.x,w0.y,w0.z,w0.w, w1.x,w1.y,w1.z,w1.w, w2.x,w2.y,w2.z,w2.w};
#pragma unroll
    for (int j = 0; j < 12; ++j) {
      acc[0][j] += va0 * wb[j];
      acc[1][j] += va1 * wb[j];
      acc[2][j] += va2 * wb[j];
      acc[3][j] += va3 * wb[j];
    }
  }

  // store
  if (pj == 1) {
    float* ktp = ws + WS_KT + nw * PD;
#pragma unroll
    for (int a = 0; a < 4; ++a) {
      int r = rh * 64 + ty * 4 + a;
#pragma unroll
      for (int j = 0; j < 12; ++j)
        ktp[(tx * 12 + j) * P + r] = acc[a][j];
    }
  } else {
    float* outp = ws + ((pj == 0) ? WS_Q : WS_VO) + nw * PD + (rh * 64) * D;
    float4 bq4[3];
    if (pj == 0) {
      const float4* bp = (const float4*)(bq + tx * 12);
      bq4[0] = bp[0]; bq4[1] = bp[1]; bq4[2] = bp[2];
    }
#pragma unroll
    for (int a = 0; a < 4; ++a) {
      float* orow = outp + (ty * 4 + a) * D + tx * 12;
#pragma unroll
      for (int q = 0; q < 3; ++q) {
        float4 o;
        o.x = acc[a][4*q+0]; o.y = acc[a][4*q+1];
        o.z = acc[a][4*q+2]; o.w = acc[a][4*q+3];
        if (pj == 0) {
          o.x = scale0 * o.x + bq4[q].x; o.y = scale0 * o.y + bq4[q].y;
          o.z = scale0 * o.z + bq4[q].z; o.w = scale0 * o.w + bq4[q].w;
        }
        *(float4*)(orow + 4 * q) = o;
      }
    }
  }

  if (bid == 0 && t < GCH) {
    float a = b_up[t];
    for (int j = 0; j < LCH; ++j) a += w_up[t * LCH + j] * mb[j];
    ws[WS_SCALE + t] = 1.f / (1.f + __expf(-a));
  }
}

// Attn: 1-wave blocks (64 thr); per-row data is block-uniform -> SALU/s_load.
// Lane owns columns {lane, 64+lane} of 4 rows. Zero LDS. Rank via u64 keys
// (uniform side SALU-built), softmax in-wave, PV via readlane broadcast.
__global__ __launch_bounds__(64, 2) void attn_kernel(const float* __restrict__ attn,
    const float* __restrict__ bo, const float* __restrict__ ws,
    float* __restrict__ out) {
  int lane = threadIdx.x;
  int nw = blockIdx.x >> 5;
  int p0 = (blockIdx.x & 31) << 2;
  const float* Kt  = ws + WS_KT + nw * PD;
  const float* VO  = ws + WS_VO + nw * PD;
  const float* Qb  = ws + WS_Q  + nw * PD + p0 * D;
  const float* Ab  = attn + (size_t)(nw * P + p0) * P;
  const float* scl = ws + WS_SCALE;

  // per-lane keys for my 2 columns of each of 4 rows
  ull k0[4], k1[4];
#pragma unroll
  for (int r = 0; r < 4; ++r) {
    k0[r] = make_key(Ab[r * P + lane], lane);
    k1[r] = make_key(Ab[r * P + 64 + lane], 64 + lane);
  }

  // exact stable top-100 rank; uniform A loads chunked (8/row) to stay in SGPRs
  int c0_[4] = {0,0,0,0}, c1_[4] = {0,0,0,0};
  for (int jb = 0; jb < P; jb += 8) {
    float aj[4][8];
#pragma unroll
    for (int rr = 0; rr < 4; ++rr)
#pragma unroll
      for (int i = 0; i < 8; ++i) aj[rr][i] = Ab[rr * P + jb + i];
#pragma unroll
    for (int i = 0; i < 8; ++i) {
      int j = jb + i;
#pragma unroll
      for (int rr = 0; rr < 4; ++rr) {
        ull kj = make_key(aj[rr][i], j);   // uniform: SALU build
        c0_[rr] += (kj > k0[rr]) ? 1 : 0;  // v_cmp_gt_u64 + addc
        c1_[rr] += (kj > k1[rr]) ? 1 : 0;
      }
    }
  }

  // S[r][col] = q_r . k_col ; q uniform (chunked), Kt coalesced per-lane
  float s0[4] = {0,0,0,0}, s1[4] = {0,0,0,0};
  for (int cb = 0; cb < D; cb += 8) {
    float q[4][8];
#pragma unroll
    for (int rr = 0; rr < 4; ++rr)
#pragma unroll
      for (int i = 0; i < 8; ++i) q[rr][i] = Qb[rr * D + cb + i];
#pragma unroll
    for (int i = 0; i < 8; ++i) {
      int c = cb + i;
      float kv0 = Kt[c * P + lane];
      float kv1 = Kt[c * P + 64 + lane];
#pragma unroll
      for (int rr = 0; rr < 4; ++rr) {
        s0[rr] += q[rr][i] * kv0;
        s1[rr] += q[rr][i] * kv1;
      }
    }
  }

  // keep mask, position among kept, scale gather, softmax, T weights
  float t0[4], t1[4];
  ull lm = (1ull << lane) - 1ull;
#pragma unroll
  for (int rr = 0; rr < 4; ++rr) {
    bool kp0 = c0_[rr] < SIM, kp1 = c1_[rr] < SIM;
    ull b0 = __ballot(kp0), b1 = __ballot(kp1);
    int pos0 = __popcll(b0 & lm);
    int pos1 = __popcll(b0) + __popcll(b1 & lm);
    float sv0 = kp0 ? scl[1 + pos0] : 0.f;
    float sv1 = kp1 ? scl[1 + pos1] : 0.f;
    float x0 = kp0 ? sv0 * s0[rr] * RSQRT96 : -1e30f;
    float x1 = kp1 ? sv1 * s1[rr] * RSQRT96 : -1e30f;
    float m = fmaxf(x0, x1);
#pragma unroll
    for (int off = 1; off < 64; off <<= 1) m = fmaxf(m, __shfl_xor(m, off));
    float e0 = kp0 ? __expf(x0 - m) : 0.f;
    float e1 = kp1 ? __expf(x1 - m) : 0.f;
    float s = e0 + e1;
#pragma unroll
    for (int off = 1; off < 64; off <<= 1) s += __shfl_xor(s, off);
    float inv = 1.f / s;
    t0[rr] = e0 * inv * sv0;
    t1[rr] = e1 * inv * sv1;
  }

  // out[r][c] = sum_j T[r][j] * VO[j][c] + b_o[c]; T broadcast via readlane
  float o0[4] = {0,0,0,0}, o1[4] = {0,0,0,0};
  int lane2 = (lane < 32) ? (64 + lane) : 95;  // clamp; junk unused
#pragma unroll 4
  for (int j = 0; j < 64; ++j) {
    float vo0 = VO[j * D + lane];
    float vo1 = VO[j * D + lane2];
#pragma unroll
    for (int rr = 0; rr < 4; ++rr) {
      float tv = __int_as_float(__builtin_amdgcn_readlane(__float_as_int(t0[rr]), j));
      o0[rr] += tv * vo0;
      o1[rr] += tv * vo1;
    }
  }
#pragma unroll 4
  for (int j = 0; j < 64; ++j) {
    float vo0 = VO[(64 + j) * D + lane];
    float vo1 = VO[(64 + j) * D + lane2];
#pragma unroll
    for (int rr = 0; rr < 4; ++rr) {
      float tv = __int_as_float(__builtin_amdgcn_readlane(__float_as_int(t1[rr]), j));
      o0[rr] += tv * vo0;
      o1[rr] += tv * vo1;
    }
  }
  float bb0 = bo[lane];
  float bb1 = bo[lane2];
  float* op = out + (size_t)(nw * P + p0) * D;
#pragma unroll
  for (int rr = 0; rr < 4; ++rr) {
    op[rr * D + lane] = o0[rr] + bb0;
    if (lane < 32) op[rr * D + 64 + lane] = o1[rr] + bb1;
  }
}

extern "C" void kernel_launch(void* const* d_in, const int* in_sizes, int n_in,
                              void* d_out, int out_size, void* d_ws, size_t ws_size,
                              hipStream_t stream) {
  const float* attn = (const float*)d_in[0];
  const float* v    = (const float*)d_in[1];
  const float* mb   = (const float*)d_in[2];
  // d_in[3]=w_sub, d_in[4]=b_sub: dead (softmax over singleton axis == 1)
  const float* w_up = (const float*)d_in[5];
  const float* b_up = (const float*)d_in[6];
  const float* w_q  = (const float*)d_in[7];
  const float* b_q  = (const float*)d_in[8];
  const float* w_k  = (const float*)d_in[9];
  // d_in[10]=b_k: constant shift per row -> drops out of softmax, unused
  const float* w_o  = (const float*)d_in[11];
  const float* b_o  = (const float*)d_in[12];
  float* out = (float*)d_out;
  float* ws = (float*)d_ws;

  hipLaunchKernelGGL(proj_kernel, dim3(NW * 6), dim3(128), 0, stream,
                     v, w_q, b_q, w_k, w_o, mb, w_up, b_up, ws);
  hipLaunchKernelGGL(attn_kernel, dim3(NW * 32), dim3(64), 0, stream,
                     attn, b_o, ws, out);
}